// Round 6
// baseline (241.569 us; speedup 1.0000x reference)
//
#include <hip/hip_runtime.h>

// cumprod along dim 1 of (ROWS, N) fp32, row-major — two-pass, barrier-free.
//
// Five structurally different single-pass kernels all pinned at ~81 us /
// 2.5 TB/s while fillBuffer hits 6.7 TB/s on the same chip: the shared
// trait was load->row-wide-dependent-scan->store convoys per wave.
// This version decouples streaming from scanning:
//   Pass 1: per 1024-elem segment, wave computes the segment product
//           (pure read stream + 4B write; no LDS, no barrier).
//   Pass 2: wave re-reads its segment (L3-resident: input 128 MiB < 256 MiB
//           L3), folds in the product of preceding segments' seeds, does the
//           register DPP scan, nontemporal-stores the result.
// Seeds live in d_ws (ROWS * 8 floats = 128 KB). Stream order guarantees
// pass1 -> pass2 visibility. Fallback: verified single-kernel scan if the
// workspace is too small.

#define N    8192
#define SEG  1024                 // elements per wave-segment
#define SPR  (N / SEG)            // 8 segments per row
#define QV   (SEG / 256)          // 4 dwordx4 per lane
#define T    256                  // 4 waves per block
#define WPB  (T / 64)

typedef float f32x4 __attribute__((ext_vector_type(4)));

__device__ __forceinline__ float readlane63(float x) {
    return __builtin_bit_cast(float,
        __builtin_amdgcn_readlane(__builtin_bit_cast(int, x), 63));
}

template<int CTRL, int RM, int BM>
__device__ __forceinline__ float dpp_id1(float x) {
    int r = __builtin_amdgcn_update_dpp(
        __builtin_bit_cast(int, 1.0f), __builtin_bit_cast(int, x),
        CTRL, RM, BM, false);
    return __builtin_bit_cast(float, r);
}

// Wave64 inclusive product-scan, pure VALU (verified in Round 5).
__device__ __forceinline__ float wave_scan_mul(float x) {
    x *= dpp_id1<0x111, 0xf, 0xf>(x);   // row_shr:1
    x *= dpp_id1<0x112, 0xf, 0xf>(x);   // row_shr:2
    x *= dpp_id1<0x114, 0xf, 0xf>(x);   // row_shr:4
    x *= dpp_id1<0x118, 0xf, 0xf>(x);   // row_shr:8
    x *= dpp_id1<0x142, 0xa, 0xf>(x);   // row_bcast:15
    x *= dpp_id1<0x143, 0xc, 0xf>(x);   // row_bcast:31
    return x;
}

// ---------------- Pass 1: segment products ----------------
__global__ __launch_bounds__(T) void seed_kernel(
    const float* __restrict__ x, float* __restrict__ seeds, int n_rows)
{
    const int gw   = blockIdx.x * WPB + (threadIdx.x >> 6);
    const int lane = threadIdx.x & 63;
    const int row  = gw / SPR;
    const int seg  = gw % SPR;
    if (row >= n_rows) return;

    const float* __restrict__ xr = x + (size_t)row * N + (size_t)seg * SEG;

    f32x4 d[QV];
#pragma unroll
    for (int v = 0; v < QV; ++v)
        d[v] = *reinterpret_cast<const f32x4*>(xr + (v * 64 + lane) * 4);

    // per-lane product of 16 elems (tree)
    float q[QV];
#pragma unroll
    for (int v = 0; v < QV; ++v)
        q[v] = (d[v].x * d[v].y) * (d[v].z * d[v].w);
    const float p = (q[0] * q[1]) * (q[2] * q[3]);

    const float inc = wave_scan_mul(p);        // lane63 holds segment product
    if (lane == 63) seeds[(size_t)row * SPR + seg] = inc;
}

// ---------------- Pass 2: apply seeds + in-segment scan ----------------
__global__ __launch_bounds__(T) void scan_kernel(
    const float* __restrict__ x, const float* __restrict__ seeds,
    float* __restrict__ out, int n_rows)
{
    const int gw   = blockIdx.x * WPB + (threadIdx.x >> 6);
    const int lane = threadIdx.x & 63;
    const int row  = gw / SPR;
    const int seg  = gw % SPR;
    if (row >= n_rows) return;

    const size_t base = (size_t)row * N + (size_t)seg * SEG;

    f32x4 d[QV];
#pragma unroll
    for (int v = 0; v < QV; ++v)
        d[v] = *reinterpret_cast<const f32x4*>(x + base + (v * 64 + lane) * 4);

    // product of seeds of preceding segments in this row (wave-uniform)
    const float* __restrict__ sr = seeds + (size_t)row * SPR;
    const f32x4 s0 = *reinterpret_cast<const f32x4*>(sr);
    const f32x4 s1 = *reinterpret_cast<const f32x4*>(sr + 4);
    float spre = 1.0f;
    spre *= (seg > 0) ? s0.x : 1.0f;
    spre *= (seg > 1) ? s0.y : 1.0f;
    spre *= (seg > 2) ? s0.z : 1.0f;
    spre *= (seg > 3) ? s0.w : 1.0f;
    spre *= (seg > 4) ? s1.x : 1.0f;
    spre *= (seg > 5) ? s1.y : 1.0f;
    spre *= (seg > 6) ? s1.z : 1.0f;

    // in-segment scan (Round-5-verified machinery, carry seeded with spre)
    float carry = spre;
    float coef[QV];
#pragma unroll
    for (int v = 0; v < QV; ++v) {
        d[v].y *= d[v].x;
        d[v].z *= d[v].y;
        d[v].w *= d[v].z;
        const float t = d[v].w;
        const float e = __shfl_up(t, 1, 64);
        const float ep = (lane == 0) ? 1.0f : e;
        const float exc = wave_scan_mul(ep);    // exclusive over quad totals
        coef[v] = carry * exc;
        carry  *= readlane63(exc * t);
    }

#pragma unroll
    for (int v = 0; v < QV; ++v) {
        f32x4 o = d[v];
        o.x *= coef[v]; o.y *= coef[v]; o.z *= coef[v]; o.w *= coef[v];
        __builtin_nontemporal_store(
            o, reinterpret_cast<f32x4*>(out + base + (v * 64 + lane) * 4));
    }
}

// ---------------- Fallback: Round-5 single-pass kernel (verified) ----------------
__global__ __launch_bounds__(T) void cumprod_rows_fallback(
    const float* __restrict__ x, float* __restrict__ out, int n_rows)
{
    __shared__ float wsum[WPB];
    const int row = blockIdx.x;
    if (row >= n_rows) return;
    const int tid  = threadIdx.x;
    const int lane = tid & 63;
    const int wid  = tid >> 6;
    const size_t base = (size_t)row * N + (size_t)wid * (N / WPB);
    const float* __restrict__ xr   = x   + base;
    float*       __restrict__ outr = out + base;

    f32x4 d[8];
#pragma unroll
    for (int v = 0; v < 8; ++v)
        d[v] = *reinterpret_cast<const f32x4*>(xr + v * 256 + lane * 4);
    float carry = 1.0f, coef[8];
#pragma unroll
    for (int v = 0; v < 8; ++v) {
        d[v].y *= d[v].x; d[v].z *= d[v].y; d[v].w *= d[v].z;
        const float t = d[v].w;
        const float e = __shfl_up(t, 1, 64);
        const float ep = (lane == 0) ? 1.0f : e;
        const float exc = wave_scan_mul(ep);
        coef[v] = carry * exc;
        carry  *= readlane63(exc * t);
    }
    if (lane == 0) wsum[wid] = carry;
    __syncthreads();
    float wpre = 1.0f;
#pragma unroll
    for (int w = 0; w < WPB - 1; ++w)
        if (w < wid) wpre *= wsum[w];
#pragma unroll
    for (int v = 0; v < 8; ++v) {
        const float f = wpre * coef[v];
        f32x4 o = d[v];
        o.x *= f; o.y *= f; o.z *= f; o.w *= f;
        __builtin_nontemporal_store(
            o, reinterpret_cast<f32x4*>(outr + v * 256 + lane * 4));
    }
}

extern "C" void kernel_launch(void* const* d_in, const int* in_sizes, int n_in,
                              void* d_out, int out_size, void* d_ws, size_t ws_size,
                              hipStream_t stream)
{
    const float* x   = (const float*)d_in[0];
    float*       out = (float*)d_out;
    const int n_rows = in_sizes[0] / N;               // 4096
    const size_t seed_bytes = (size_t)n_rows * SPR * sizeof(float);

    if (d_ws != nullptr && ws_size >= seed_bytes) {
        float* seeds = (float*)d_ws;
        const int nblk = (n_rows * SPR) / WPB;        // 8192 blocks
        seed_kernel<<<nblk, T, 0, stream>>>(x, seeds, n_rows);
        scan_kernel<<<nblk, T, 0, stream>>>(x, seeds, out, n_rows);
    } else {
        cumprod_rows_fallback<<<n_rows, T, 0, stream>>>(x, out, n_rows);
    }
}

// Round 7
// 228.465 us; speedup vs baseline: 1.0574x; 1.0574x over previous
//
#include <hip/hip_runtime.h>

// cumprod along dim 1 of (ROWS, N) fp32, row-major.
// One wave per row; per-wave private LDS double-buffer filled by
// global_load_lds DMA with COUNTED vmcnt waits (never drained to 0 in
// the main loop), so every wave keeps >=4KB of loads in flight during
// its scan phase. No barriers anywhere. This attacks the measured
// failure mode of rounds 0-6: bursty load->scan->store convoys giving
// the memory system a ~40% duty cycle (2.5 of 6.3 TB/s).
//
// Issue-order argument for vmcnt counts (pinned by asm memory clobbers):
//   iter t issues loads(t+1) [4 ops], then waits, then stores(t) [4 ops].
//   At iter t's wait, ops issued after loads(t) are stores(t-1)+loads(t+1)
//   = 8, so vmcnt(8) guarantees loads(t) retired. t=0 / t=NT-1: vmcnt(4).

#define N     8192
#define T     256
#define WPB   (T / 64)        // 4 waves per block
#define TILE  1024            // elems per tile = 4 KB
#define NT    (N / TILE)      // 8 tiles per row
#define CHK   (TILE / 256)    // 4 chunks of 256 elems per tile

typedef float f32x4 __attribute__((ext_vector_type(4)));
typedef const __attribute__((address_space(1))) float glb_f;
typedef __attribute__((address_space(3))) float lds_f;

__device__ __forceinline__ float readlane63(float x) {
    return __builtin_bit_cast(float,
        __builtin_amdgcn_readlane(__builtin_bit_cast(int, x), 63));
}

template<int CTRL, int RM, int BM>
__device__ __forceinline__ float dpp_id1(float x) {
    int r = __builtin_amdgcn_update_dpp(
        __builtin_bit_cast(int, 1.0f), __builtin_bit_cast(int, x),
        CTRL, RM, BM, false);
    return __builtin_bit_cast(float, r);
}

// Wave64 inclusive product-scan, pure VALU (verified rounds 5-6).
__device__ __forceinline__ float wave_scan_mul(float x) {
    x *= dpp_id1<0x111, 0xf, 0xf>(x);   // row_shr:1
    x *= dpp_id1<0x112, 0xf, 0xf>(x);   // row_shr:2
    x *= dpp_id1<0x114, 0xf, 0xf>(x);   // row_shr:4
    x *= dpp_id1<0x118, 0xf, 0xf>(x);   // row_shr:8
    x *= dpp_id1<0x142, 0xa, 0xf>(x);   // row_bcast:15
    x *= dpp_id1<0x143, 0xc, 0xf>(x);   // row_bcast:31
    return x;
}

__global__ __launch_bounds__(T) void cumprod_rows_kernel(
    const float* __restrict__ x, float* __restrict__ out, int n_rows)
{
    __shared__ float lds[WPB][2][TILE];   // 32 KB: per-wave 2x4KB buffers

    const int lane = threadIdx.x & 63;
    const int wid  = threadIdx.x >> 6;
    const int row  = blockIdx.x * WPB + wid;
    if (row >= n_rows) return;            // no barriers -> safe early exit

    const float* __restrict__ xr   = x   + (size_t)row * N;
    float*       __restrict__ outr = out + (size_t)row * N;

    // ---- prologue: DMA tile 0 into buffer 0 ----
#pragma unroll
    for (int c = 0; c < CHK; ++c)
        __builtin_amdgcn_global_load_lds(
            (glb_f*)(xr + c * 256 + lane * 4),
            (lds_f*)&lds[wid][0][c * 256], 16, 0, 0);

    float carry = 1.0f;

#pragma unroll
    for (int t = 0; t < NT; ++t) {
        const int b = t & 1;

        // ---- issue next tile's DMA before waiting on this one ----
        if (t + 1 < NT) {
#pragma unroll
            for (int c = 0; c < CHK; ++c)
                __builtin_amdgcn_global_load_lds(
                    (glb_f*)(xr + (t + 1) * TILE + c * 256 + lane * 4),
                    (lds_f*)&lds[wid][b ^ 1][c * 256], 16, 0, 0);
        }

        // ---- counted wait: tile t's 4 loads retired, rest in flight ----
        if (t == 0 || t == NT - 1)
            asm volatile("s_waitcnt vmcnt(4)" ::: "memory");
        else
            asm volatile("s_waitcnt vmcnt(8)" ::: "memory");
        __builtin_amdgcn_sched_barrier(0);

        // ---- scan tile t from LDS (register DPP machinery) ----
        f32x4 d[CHK];
        float coef[CHK];
#pragma unroll
        for (int c = 0; c < CHK; ++c) {
            d[c] = *reinterpret_cast<const f32x4*>(
                       &lds[wid][b][c * 256 + lane * 4]);   // ds_read_b128
            d[c].y *= d[c].x;
            d[c].z *= d[c].y;
            d[c].w *= d[c].z;
            const float tt = d[c].w;
            const float e  = __shfl_up(tt, 1, 64);
            const float ep = (lane == 0) ? 1.0f : e;
            const float exc = wave_scan_mul(ep);   // excl. scan of quad totals
            coef[c] = carry * exc;
            carry  *= readlane63(exc * tt);        // chunk total (uniform)
        }

        // ---- nontemporal coalesced stores ----
#pragma unroll
        for (int c = 0; c < CHK; ++c) {
            f32x4 o = d[c];
            o.x *= coef[c]; o.y *= coef[c];
            o.z *= coef[c]; o.w *= coef[c];
            __builtin_nontemporal_store(
                o, reinterpret_cast<f32x4*>(outr + t * TILE + c * 256 + lane * 4));
        }
    }
}

extern "C" void kernel_launch(void* const* d_in, const int* in_sizes, int n_in,
                              void* d_out, int out_size, void* d_ws, size_t ws_size,
                              hipStream_t stream)
{
    const float* x   = (const float*)d_in[0];
    float*       out = (float*)d_out;
    const int n_rows = in_sizes[0] / N;                 // 4096
    const int nblk   = (n_rows + WPB - 1) / WPB;        // 1024
    cumprod_rows_kernel<<<nblk, T, 0, stream>>>(x, out, n_rows);
}